// Round 7
// baseline (123.184 us; speedup 1.0000x reference)
//
#include <hip/hip_runtime.h>
#include <hip/hip_bf16.h>
#include <stdint.h>

#define K_DIM 1024
#define N_DIM 1024
#define NKT 16   // K / 64

typedef __attribute__((ext_vector_type(8))) short  short8;
typedef __attribute__((ext_vector_type(4))) float  f32x4;
typedef __attribute__((ext_vector_type(4))) unsigned int u32x4;

__device__ __forceinline__ ushort f2bf(float f) {
  union { float f; uint32_t u; } v; v.f = f;
  uint32_t r = v.u + 0x7FFFu + ((v.u >> 16) & 1u);
  return (ushort)(r >> 16);
}
__device__ __forceinline__ uint32_t pack_bf2(float a, float b) {
  __hip_bfloat162 h = __float22bfloat162_rn(make_float2(a, b));
  union { __hip_bfloat162 h; uint32_t u; } c; c.h = h;
  return c.u;
}

// ---------------- kernel 1: materialize Toeplitz matrix as bf16 -------------
__global__ __launch_bounds__(256) void build_T_kernel(
    const float* __restrict__ fr, const float* __restrict__ fc,
    ushort* __restrict__ T) {
  int idx = blockIdx.x * 256 + threadIdx.x;
  int o  = idx >> 7;
  int i0 = (idx & 127) << 3;
  short8 v;
#pragma unroll
  for (int j = 0; j < 8; ++j) {
    int d = o - (i0 + j);
    float f = (d >= 0) ? fc[d] : fr[-d];
    v[j] = (short)f2bf(f);
  }
  *reinterpret_cast<short8*>(T + (size_t)idx * 8) = v;
}

// ---------------- kernel 1b: convert x fp32 -> bf16 -------------------------
__global__ __launch_bounds__(256) void convert_x_kernel(
    const float* __restrict__ X, ushort* __restrict__ XB) {
  size_t idx = ((size_t)blockIdx.x * 256 + threadIdx.x) * 8;
  const size_t stride = (size_t)2048 * 256 * 8;
#pragma unroll
  for (int it = 0; it < 8; ++it) {
    f32x4 a = *reinterpret_cast<const f32x4*>(X + idx);
    f32x4 b = *reinterpret_cast<const f32x4*>(X + idx + 4);
    u32x4 p;
    p.x = pack_bf2(a.x, a.y); p.y = pack_bf2(a.z, a.w);
    p.z = pack_bf2(b.x, b.y); p.w = pack_bf2(b.z, b.w);
    *reinterpret_cast<u32x4*>(XB + idx) = p;
    idx += stride;
  }
}

// -------- kernel 2: 256x256 bf16, 4-phase/K-tile 8-phase/iter template ------
__global__ __launch_bounds__(512, 2) void gemm_bf16_8p(
    const ushort* __restrict__ XB, const ushort* __restrict__ T,
    const float* __restrict__ bias, float* __restrict__ Out) {
  // LDS: buf c at c*65536: A [256rows][128B] @0, B @32768. 128 KiB total.
  __shared__ alignas(16) char smem[131072];

  const int tid  = threadIdx.x;
  const int lane = tid & 63;
  const int wv   = tid >> 6;
  const int wm   = wv >> 2, wn = wv & 3;      // 2x4 wave grid, 128x64 tiles
  const int cc   = lane & 15, kg = lane >> 4;

  // XCD swizzle: 512 blocks = 8 xcd * 64; 4 consecutive share an m-panel.
  const int swz = (blockIdx.x & 7) * 64 + (blockIdx.x >> 3);
  const int m0 = (swz >> 2) * 256;
  const int n0 = (swz & 3) * 256;

  // staging: per half-tile (128 rows x 64k) each thread does 2 x 16B DMA.
  const int r0  = tid >> 3;
  const int kbs = ((((tid & 7) * 16) ^ ((r0 & 7) << 4)) >> 1);  // pre-swizzled k
  const ushort* aSrc = XB + (size_t)(m0 + r0) * K_DIM + kbs;
  const ushort* bSrc = T  + (size_t)(n0 + r0) * K_DIM + kbs;
  const int dOff = tid * 16;

  // fragment read offsets (swizzled on read, matching pre-swizzled source)
  const int kx0 = (kg * 16) ^ ((cc & 7) << 4);
  const int kx1 = (64 + kg * 16) ^ ((cc & 7) << 4);
  const int aRow = (wm * 128 + cc) * 128;          // + mf*2048
  const int bRow = 32768 + (wn * 64 + cc) * 128;   // + nf*2048

  short8 a03[4][2], a47[4][2], b01[2][2], b23[2][2];
  f32x4  acc[8][4] = {};

#define SB0() __builtin_amdgcn_sched_barrier(0)
#define BAR() __builtin_amdgcn_s_barrier()
#define GATE4 asm volatile("s_waitcnt vmcnt(4)" ::: "memory")
#define GATE0 asm volatile("s_waitcnt vmcnt(0)" ::: "memory")
#define NOGATE ((void)0)

#define RD(buf, off) (*reinterpret_cast<const short8*>(smem + (buf) * 65536 + (off)))

#define READ_A(C, arr, mfb)                                                 \
  { _Pragma("unroll")                                                       \
    for (int mf = 0; mf < 4; ++mf) {                                        \
      arr[mf][0] = RD(C, aRow + ((mfb) + mf) * 2048 + kx0);                 \
      arr[mf][1] = RD(C, aRow + ((mfb) + mf) * 2048 + kx1);                 \
    } }

#define READ_B(C, arr, nfb)                                                 \
  { _Pragma("unroll")                                                       \
    for (int nf = 0; nf < 2; ++nf) {                                        \
      arr[nf][0] = RD(C, bRow + ((nfb) + nf) * 2048 + kx0);                 \
      arr[nf][1] = RD(C, bRow + ((nfb) + nf) * 2048 + kx1);                 \
    } }

#define STAGE_A(kt, h, buf)                                                 \
  { _Pragma("unroll")                                                       \
    for (int s = 0; s < 2; ++s) {                                           \
      const ushort* src = aSrc + (size_t)((h) * 128 + s * 64) * K_DIM + (kt) * 64; \
      char* dst = smem + (buf) * 65536 + (h) * 16384 + s * 8192 + dOff;     \
      __builtin_amdgcn_global_load_lds(                                     \
          (const __attribute__((address_space(1))) void*)src,               \
          (__attribute__((address_space(3))) void*)dst, 16, 0, 0);          \
    } }

#define STAGE_B(kt, h, buf)                                                 \
  { _Pragma("unroll")                                                       \
    for (int s = 0; s < 2; ++s) {                                           \
      const ushort* src = bSrc + (size_t)((h) * 128 + s * 64) * K_DIM + (kt) * 64; \
      char* dst = smem + (buf) * 65536 + 32768 + (h) * 16384 + s * 8192 + dOff; \
      __builtin_amdgcn_global_load_lds(                                     \
          (const __attribute__((address_space(1))) void*)src,               \
          (__attribute__((address_space(3))) void*)dst, 16, 0, 0);          \
    } }

#define MFMA8(Aa, Bb, mfb, nfb)                                             \
  { __builtin_amdgcn_s_setprio(1);                                         \
    _Pragma("unroll")                                                       \
    for (int mf = 0; mf < 4; ++mf)                                          \
      _Pragma("unroll")                                                     \
      for (int nf = 0; nf < 2; ++nf) {                                      \
        acc[(mfb) + mf][(nfb) + nf] = __builtin_amdgcn_mfma_f32_16x16x32_bf16( \
            Aa[mf][0], Bb[nf][0], acc[(mfb) + mf][(nfb) + nf], 0, 0, 0);    \
        acc[(mfb) + mf][(nfb) + nf] = __builtin_amdgcn_mfma_f32_16x16x32_bf16( \
            Aa[mf][1], Bb[nf][1], acc[(mfb) + mf][(nfb) + nf], 0, 0, 0);    \
      }                                                                     \
    __builtin_amdgcn_s_setprio(0); }

// One K-tile = 4 phases. Stage slots (derived hazard windows, see analysis):
//   P1: Ah1(t+1)->N   P2: Bh1(t+1)->N   P3: Bh0(t+2)->C   P4: Ah0(t+2)->C
// Single counted gate vmcnt(4) at P4-end: drains through Bh1(t+1), leaves
// the 2 half-tiles (4 loads) of t+2 in flight.
#define GROUP(T, C, N, DO12, DO34, GATESTMT)                                \
  { /* P1 */                                                                \
    READ_A(C, a03, 0);                                                      \
    READ_B(C, b01, 0);                                                      \
    if (DO12) STAGE_A((T) + 1, 1, N);                                       \
    BAR();                                                                  \
    MFMA8(a03, b01, 0, 0);                                                  \
    BAR();                                                                  \
    /* P2 */                                                                \
    READ_B(C, b23, 2);                                                      \
    if (DO12) STAGE_B((T) + 1, 1, N);                                       \
    BAR();                                                                  \
    MFMA8(a03, b23, 0, 2);                                                  \
    BAR();                                                                  \
    /* P3 */                                                                \
    READ_A(C, a47, 4);                                                      \
    if (DO34) STAGE_B((T) + 2, 0, C);                                       \
    BAR();                                                                  \
    MFMA8(a47, b23, 4, 2);                                                  \
    BAR();                                                                  \
    /* P4 */                                                                \
    if (DO34) STAGE_A((T) + 2, 0, C);                                       \
    BAR();                                                                  \
    MFMA8(a47, b01, 4, 0);                                                  \
    GATESTMT;                                                               \
    BAR();                                                                  \
  }

  // ---- prologue: stage kt0 fully + kt1 h0-halves, in steady-state order ----
  STAGE_B(0, 0, 0); SB0();
  STAGE_A(0, 0, 0); SB0();
  STAGE_A(0, 1, 0); SB0();
  STAGE_B(0, 1, 0); SB0();
  STAGE_B(1, 0, 1); SB0();
  STAGE_A(1, 0, 1); SB0();
  GATE4;                       // kt0 complete; kt1-h0 pair still in flight
  BAR();

#pragma unroll 1
  for (int i = 0; i < 7; ++i) {
    const int t = 2 * i;
    GROUP(t,     0, 1, 1, 1, GATE4);
    GROUP(t + 1, 1, 0, 1, 1, GATE4);
  }
  GROUP(14, 0, 1, 1, 0, GATE0);
  GROUP(15, 1, 0, 0, 0, NOGATE);

  // ---- epilogue: bias + fp32 store ----
#pragma unroll
  for (int nf = 0; nf < 4; ++nf) {
    const int col = n0 + wn * 64 + nf * 16 + cc;
    const float bv = bias[col];
#pragma unroll
    for (int mf = 0; mf < 8; ++mf) {
      const int row0 = m0 + wm * 128 + mf * 16 + kg * 4;
      float* op = Out + (size_t)row0 * N_DIM + col;
#pragma unroll
      for (int j = 0; j < 4; ++j)
        op[(size_t)j * N_DIM] = acc[mf][nf][j] + bv;
    }
  }
#undef GROUP
#undef MFMA8
#undef STAGE_A
#undef STAGE_B
#undef READ_A
#undef READ_B
#undef RD
#undef SB0
#undef BAR
#undef GATE4
#undef GATE0
#undef NOGATE
}

// --------- fallback kernel (ws < 66MB): R4 A-in-reg structure ---------------
__global__ __launch_bounds__(512, 2) void toeplitz_gemm_f32(
    const float* __restrict__ X, const ushort* __restrict__ T,
    const float* __restrict__ bias, float* __restrict__ Out) {
  __shared__ alignas(16) char smem[65536];
  const int tid  = threadIdx.x;
  const int lane = tid & 63;
  const int wv   = tid >> 6;
  const int cc   = lane & 15, kg = lane >> 4;
  const int swz = (blockIdx.x & 7) * 64 + (blockIdx.x >> 3);
  const int m0 = (swz >> 2) * 256;
  const int n0 = (swz & 3) * 256;
  const int brow = tid >> 3;
  const ushort* tptr = T + (size_t)(n0 + brow) * K_DIM
                         + ((((tid & 7) * 16) ^ ((brow & 7) << 4)) >> 1);
  const int bLds = tid * 16;
  const float* xptr = X + (size_t)(m0 + wv * 32 + cc) * K_DIM + kg * 8;
  const int bXor = (cc & 7) << 4;
  f32x4  areg[2][2][2];
  short8 afrag[2][2];
  short8 bfr[2][2][2];
  f32x4  acc[2][16] = {};
#define SB0() __builtin_amdgcn_sched_barrier(0)
#define ISSUE_A(t)                                                          \
  { _Pragma("unroll")                                                       \
    for (int mf = 0; mf < 2; ++mf)                                          \
      _Pragma("unroll")                                                     \
      for (int kk = 0; kk < 2; ++kk)                                        \
        _Pragma("unroll")                                                   \
        for (int j = 0; j < 2; ++j)                                         \
          areg[mf][kk][j] = *reinterpret_cast<const f32x4*>(                \
              xptr + (size_t)mf * 16 * K_DIM + (t) * 64 + kk * 32 + j * 4); }
#define CVT_A()                                                             \
  { _Pragma("unroll")                                                       \
    for (int mf = 0; mf < 2; ++mf)                                          \
      _Pragma("unroll")                                                     \
      for (int kk = 0; kk < 2; ++kk) {                                      \
        union { short8 s; uint32_t u[4]; } t_;                              \
        t_.u[0] = pack_bf2(areg[mf][kk][0].x, areg[mf][kk][0].y);           \
        t_.u[1] = pack_bf2(areg[mf][kk][0].z, areg[mf][kk][0].w);           \
        t_.u[2] = pack_bf2(areg[mf][kk][1].x, areg[mf][kk][1].y);           \
        t_.u[3] = pack_bf2(areg[mf][kk][1].z, areg[mf][kk][1].w);           \
        afrag[mf][kk] = t_.s;                                               \
      } }
#define ISSUE_B(t, sel)                                                     \
  { _Pragma("unroll")                                                       \
    for (int g = 0; g < 4; ++g) {                                           \
      const ushort* src = tptr + (size_t)g * 64 * K_DIM + (t) * 64;         \
      char* dst = smem + bLds + (sel) * 32768 + g * 8192;                   \
      __builtin_amdgcn_global_load_lds(                                     \
          (const __attribute__((address_space(1))) void*)src,               \
          (__attribute__((address_space(3))) void*)dst, 16, 0, 0);          \
    } }
#define READ_B(sel, nfg, set)                                               \
  { _Pragma("unroll")                                                       \
    for (int nf = 0; nf < 2; ++nf)                                          \
      _Pragma("unroll")                                                     \
      for (int kk = 0; kk < 2; ++kk)                                        \
        bfr[set][nf][kk] = *reinterpret_cast<const short8*>(                \
            smem + (sel) * 32768 +                                          \
            (((nfg) * 2 + nf) * 16 + cc) * 128 +                            \
            ((kk * 64 + kg * 16) ^ bXor)); }
#define MFMA_G(nfg, set)                                                    \
  { __builtin_amdgcn_s_setprio(1);                                         \
    _Pragma("unroll")                                                       \
    for (int mf = 0; mf < 2; ++mf)                                          \
      _Pragma("unroll")                                                     \
      for (int nf = 0; nf < 2; ++nf)                                        \
        _Pragma("unroll")                                                   \
        for (int kk = 0; kk < 2; ++kk)                                      \
          acc[mf][(nfg) * 2 + nf] = __builtin_amdgcn_mfma_f32_16x16x32_bf16( \
              afrag[mf][kk], bfr[set][nf][kk], acc[mf][(nfg) * 2 + nf],      \
              0, 0, 0);                                                      \
    __builtin_amdgcn_s_setprio(0); }
  ISSUE_B(0, 0); SB0();
  ISSUE_A(0);    SB0();
  asm volatile("s_waitcnt vmcnt(8)" ::: "memory");
  __builtin_amdgcn_s_barrier();
#pragma unroll 1
  for (int t = 0; t < NKT; ++t) {
    const int c = t & 1, n = c ^ 1;
    if (t + 1 < NKT) { ISSUE_B(t + 1, n); SB0(); }
    CVT_A();
    if (t + 1 < NKT) { ISSUE_A(t + 1); SB0(); }
    READ_B(c, 0, 0);
#pragma unroll
    for (int g = 0; g < 8; ++g) {
      if (g < 7) READ_B(c, g + 1, (g + 1) & 1);
      MFMA_G(g, g & 1);
    }
    if (t + 1 < NKT) {
      asm volatile("s_waitcnt vmcnt(8)" ::: "memory");
      __builtin_amdgcn_s_barrier();
    }
  }
#pragma unroll
  for (int nf = 0; nf < 16; ++nf) {
    const int col = n0 + nf * 16 + cc;
    const float bv = bias[col];
#pragma unroll
    for (int mf = 0; mf < 2; ++mf) {
      const int row0 = m0 + wv * 32 + mf * 16 + kg * 4;
      float* op = Out + (size_t)row0 * N_DIM + col;
#pragma unroll
      for (int j = 0; j < 4; ++j)
        op[(size_t)j * N_DIM] = acc[mf][nf][j] + bv;
    }
  }
#undef ISSUE_A
#undef CVT_A
#undef ISSUE_B
#undef READ_B
#undef MFMA_G
#undef SB0
}

// ---------------- last-resort naive fp32 ------------------------------------
__global__ __launch_bounds__(256) void toeplitz_naive(
    const float* __restrict__ x, const float* __restrict__ fr,
    const float* __restrict__ fc, const float* __restrict__ bias,
    float* __restrict__ out) {
  __shared__ float sx[1024], sfr[1024], sfc[1024];
  const int m = blockIdx.x;
  for (int i = threadIdx.x; i < 1024; i += 256) {
    sx[i]  = x[(size_t)m * 1024 + i];
    sfr[i] = fr[i];
    sfc[i] = fc[i];
  }
  __syncthreads();
  for (int q = 0; q < 4; ++q) {
    const int o = threadIdx.x + q * 256;
    float acc = bias[o];
    for (int i = 0; i <= o; ++i)       acc += sx[i] * sfc[o - i];
    for (int i = o + 1; i < 1024; ++i) acc += sx[i] * sfr[i - o];
    out[(size_t)m * 1024 + o] = acc;
  }
}

extern "C" void kernel_launch(void* const* d_in, const int* in_sizes, int n_in,
                              void* d_out, int out_size, void* d_ws, size_t ws_size,
                              hipStream_t stream) {
  const float* x    = (const float*)d_in[0];
  const float* fr   = (const float*)d_in[1];
  const float* fc   = (const float*)d_in[2];
  const float* bias = (const float*)d_in[3];
  float* out = (float*)d_out;

  const size_t T_BYTES  = (size_t)2 * 1024 * 1024;
  const size_t XB_BYTES = (size_t)32768 * 1024 * 2;

  if (ws_size >= T_BYTES + XB_BYTES) {
    ushort* T  = (ushort*)d_ws;
    ushort* XB = (ushort*)((char*)d_ws + T_BYTES);
    build_T_kernel<<<dim3(512), dim3(256), 0, stream>>>(fr, fc, T);
    convert_x_kernel<<<dim3(2048), dim3(256), 0, stream>>>(x, XB);
    gemm_bf16_8p<<<dim3(512), dim3(512), 0, stream>>>(XB, T, bias, out);
  } else if (ws_size >= T_BYTES) {
    ushort* T = (ushort*)d_ws;
    build_T_kernel<<<dim3(512), dim3(256), 0, stream>>>(fr, fc, T);
    toeplitz_gemm_f32<<<dim3(512), dim3(512), 0, stream>>>(x, T, bias, out);
  } else {
    toeplitz_naive<<<dim3(32768), dim3(256), 0, stream>>>(x, fr, fc, bias, out);
  }
}

// Round 9
// 113.486 us; speedup vs baseline: 1.0854x; 1.0854x over previous
//
#include <hip/hip_runtime.h>
#include <hip/hip_bf16.h>
#include <stdint.h>

#define K_DIM 1024
#define N_DIM 1024

typedef __attribute__((ext_vector_type(8))) short  short8;
typedef __attribute__((ext_vector_type(4))) float  f32x4;
typedef __attribute__((ext_vector_type(4))) unsigned int u32x4;

__device__ __forceinline__ ushort f2bf(float f) {
  union { float f; uint32_t u; } v; v.f = f;
  uint32_t r = v.u + 0x7FFFu + ((v.u >> 16) & 1u);
  return (ushort)(r >> 16);
}
__device__ __forceinline__ uint32_t pack_bf2(float a, float b) {
  __hip_bfloat162 h = __float22bfloat162_rn(make_float2(a, b));
  union { __hip_bfloat162 h; uint32_t u; } c; c.h = h;
  return c.u;
}

// ---------------- kernel 1: materialize Toeplitz matrix as bf16 -------------
__global__ __launch_bounds__(256) void build_T_kernel(
    const float* __restrict__ fr, const float* __restrict__ fc,
    ushort* __restrict__ T) {
  int idx = blockIdx.x * 256 + threadIdx.x;
  int o  = idx >> 7;
  int i0 = (idx & 127) << 3;
  short8 v;
#pragma unroll
  for (int j = 0; j < 8; ++j) {
    int d = o - (i0 + j);
    float f = (d >= 0) ? fc[d] : fr[-d];
    v[j] = (short)f2bf(f);
  }
  *reinterpret_cast<short8*>(T + (size_t)idx * 8) = v;
}

// ---- kernel 2: fused 256x256 8-phase GEMM; A: fp32->reg->cvt->LDS ----------
__global__ __launch_bounds__(512, 2) void gemm_fused_8p(
    const float* __restrict__ X, const ushort* __restrict__ T,
    const float* __restrict__ bias, float* __restrict__ Out) {
  // LDS buf c at c*65536: A [256r][128B] @0, B @32768. 128 KiB total.
  __shared__ alignas(16) char smem[131072];

  const int tid  = threadIdx.x;
  const int lane = tid & 63;
  const int wv   = tid >> 6;
  const int wm   = wv >> 2, wn = wv & 3;      // 2x4 wave grid, 128x64 tiles
  const int cc   = lane & 15, kg = lane >> 4;

  // XCD swizzle: 512 blocks = 8 xcd * 64; 4 consecutive share an m-panel.
  const int swz = (blockIdx.x & 7) * 64 + (blockIdx.x >> 3);
  const int m0 = (swz >> 2) * 256;
  const int n0 = (swz & 3) * 256;

  const int r0 = tid >> 3;
  // B staging: DMA with pre-swizzled source, linear LDS dest.
  const ushort* bSrc = T + (size_t)(n0 + r0) * K_DIM
                         + ((((tid & 7) * 16) ^ ((r0 & 7) << 4)) >> 1);
  const int dOff = tid * 16;
  // A staging: fp32 global -> reg -> cvt_pk -> swizzled ds_write_b128.
  const float* aSrc = X + (size_t)(m0 + r0) * K_DIM + (tid & 7) * 8;
  const int aWoff = r0 * 128 + (((tid & 7) * 16) ^ ((r0 & 7) << 4));

  // fragment read offsets (swizzled read matches both stage paths)
  const int kx0 = (kg * 16) ^ ((cc & 7) << 4);
  const int kx1 = (64 + kg * 16) ^ ((cc & 7) << 4);
  const int aRow = (wm * 128 + cc) * 128;          // + mf*2048
  const int bRow = 32768 + (wn * 64 + cc) * 128;   // + nf*2048

  short8 afr[4][2];               // reused: a03 in P1-P2, a47 in P3-P4
  short8 bfr[2][2];               // reused: b01 P1, b23 P2-P3, b01 again P4
  f32x4  aH0[2][2], aH1[2][2];    // in-flight fp32 A halves
  f32x4  acc[8][4] = {};

#define SB0() __builtin_amdgcn_sched_barrier(0)
#define BAR() __builtin_amdgcn_s_barrier()
#define LGKM0 asm volatile("s_waitcnt lgkmcnt(0)" ::: "memory")
#define GATE6 asm volatile("s_waitcnt vmcnt(6)" ::: "memory")
#define GATE0 asm volatile("s_waitcnt vmcnt(0)" ::: "memory")
#define NOGATE ((void)0)

#define RD(buf, off) (*reinterpret_cast<const short8*>(smem + (buf) * 65536 + (off)))

#define READ_A(C, mfb)                                                      \
  { _Pragma("unroll")                                                       \
    for (int mf = 0; mf < 4; ++mf) {                                        \
      afr[mf][0] = RD(C, aRow + ((mfb) + mf) * 2048 + kx0);                 \
      afr[mf][1] = RD(C, aRow + ((mfb) + mf) * 2048 + kx1);                 \
    } }

#define READ_B(C, nfb)                                                      \
  { _Pragma("unroll")                                                       \
    for (int nf = 0; nf < 2; ++nf) {                                        \
      bfr[nf][0] = RD(C, bRow + ((nfb) + nf) * 2048 + kx0);                 \
      bfr[nf][1] = RD(C, bRow + ((nfb) + nf) * 2048 + kx1);                 \
    } }

#define ALOAD(arr, kt, h)                                                   \
  { _Pragma("unroll")                                                       \
    for (int s = 0; s < 2; ++s)                                             \
      _Pragma("unroll")                                                     \
      for (int j = 0; j < 2; ++j)                                           \
        arr[s][j] = *reinterpret_cast<const f32x4*>(                        \
            aSrc + (size_t)((h) * 128 + s * 64) * K_DIM + (kt) * 64 + j * 4); }

#define AWRITE(arr, h, buf)                                                 \
  { _Pragma("unroll")                                                       \
    for (int s = 0; s < 2; ++s) {                                           \
      u32x4 p;                                                              \
      p.x = pack_bf2(arr[s][0].x, arr[s][0].y);                             \
      p.y = pack_bf2(arr[s][0].z, arr[s][0].w);                             \
      p.z = pack_bf2(arr[s][1].x, arr[s][1].y);                             \
      p.w = pack_bf2(arr[s][1].z, arr[s][1].w);                             \
      *reinterpret_cast<u32x4*>(smem + (buf) * 65536 + (h) * 16384 +        \
                                s * 8192 + aWoff) = p;                      \
    } }

#define STAGE_B(kt, h, buf)                                                 \
  { _Pragma("unroll")                                                       \
    for (int s = 0; s < 2; ++s) {                                           \
      const ushort* src = bSrc + (size_t)((h) * 128 + s * 64) * K_DIM + (kt) * 64; \
      char* dst = smem + (buf) * 65536 + 32768 + (h) * 16384 + s * 8192 + dOff; \
      __builtin_amdgcn_global_load_lds(                                     \
          (const __attribute__((address_space(1))) void*)src,               \
          (__attribute__((address_space(3))) void*)dst, 16, 0, 0);          \
    } }

#define MFMA8(mfb, nfb)                                                     \
  { __builtin_amdgcn_s_setprio(1);                                         \
    _Pragma("unroll")                                                       \
    for (int mf = 0; mf < 4; ++mf)                                          \
      _Pragma("unroll")                                                     \
      for (int nf = 0; nf < 2; ++nf) {                                      \
        acc[(mfb) + mf][(nfb) + nf] = __builtin_amdgcn_mfma_f32_16x16x32_bf16( \
            afr[mf][0], bfr[nf][0], acc[(mfb) + mf][(nfb) + nf], 0, 0, 0);  \
        acc[(mfb) + mf][(nfb) + nf] = __builtin_amdgcn_mfma_f32_16x16x32_bf16( \
            afr[mf][1], bfr[nf][1], acc[(mfb) + mf][(nfb) + nf], 0, 0, 0);  \
      }                                                                     \
    __builtin_amdgcn_s_setprio(0); }

// Stage slots per GROUP(t):
//   P1: ALOAD h0(t+2); AWRITE h1(t+1)->N      [AW implicit vmcnt(6)]
//   P2: STAGE_B h1(t+1)->N; ALOAD h1(t+2)
//   P3: (none)
//   P4: AWRITE h0(t+2)->C [vmcnt(6)]; after barrier: STAGE_B h0(t+2)->C
//   end gate vmcnt(6): retires B_h1(t+1); leaves AL_h1(t+2)[4]+B_h0(t+2)[2].
#define GROUP(T, C, N, D1, D2, GATESTMT)                                    \
  { /* P1 */                                                                \
    READ_A(C, 0); READ_B(C, 0);                                             \
    if (D2) { ALOAD(aH0, (T) + 2, 0); SB0(); }                              \
    if (D1) { AWRITE(aH1, 1, N); }                                          \
    LGKM0; BAR(); SB0();                                                    \
    MFMA8(0, 0); BAR();                                                     \
    /* P2 */                                                                \
    READ_B(C, 2);                                                           \
    if (D1) { STAGE_B((T) + 1, 1, N); SB0(); }                              \
    if (D2) { ALOAD(aH1, (T) + 2, 1); SB0(); }                              \
    LGKM0; BAR(); SB0();                                                    \
    MFMA8(0, 2); BAR();                                                     \
    /* P3 */                                                                \
    READ_A(C, 4);                                                           \
    LGKM0; BAR(); SB0();                                                    \
    MFMA8(4, 2); BAR();                                                     \
    /* P4 */                                                                \
    READ_B(C, 0);                                                           \
    if (D2) { AWRITE(aH0, 0, C); }                                          \
    LGKM0; BAR(); SB0();                                                    \
    if (D2) { STAGE_B((T) + 2, 0, C); SB0(); }                              \
    MFMA8(4, 0);                                                            \
    GATESTMT; BAR();                                                        \
  }

  // ---- prologue: buf0 = tile0 complete; buf1 = tile1 {A-h0, B-h0};
  //      in-flight entering loop: [B10:2][aH1(tile1-h1):4] ----
  ALOAD(aH0, 0, 0); SB0();
  ALOAD(aH1, 0, 1); SB0();
  STAGE_B(0, 0, 0); SB0();
  STAGE_B(0, 1, 0); SB0();
  AWRITE(aH0, 0, 0);          // implicit vmcnt(8): aH0(t0) ready
  AWRITE(aH1, 1, 0);          // implicit vmcnt(4): aH1(t0) ready
  ALOAD(aH0, 1, 0); SB0();    // tile1 h0
  STAGE_B(1, 0, 1); SB0();    // tile1 B-h0 -> buf1
  AWRITE(aH0, 0, 1);          // implicit vmcnt(2): aH0(t1) ready (B10 stays)
  ALOAD(aH1, 1, 1); SB0();    // tile1 h1 (consumed at group0 P1)
  LGKM0;
  BAR();

#pragma unroll 1
  for (int i = 0; i < 7; ++i) {
    const int t = 2 * i;
    GROUP(t,     0, 1, 1, 1, GATE6);
    GROUP(t + 1, 1, 0, 1, 1, GATE6);
  }
  GROUP(14, 0, 1, 1, 0, GATE0);
  GROUP(15, 1, 0, 0, 0, NOGATE);

  // ---- epilogue: bias + fp32 store ----
#pragma unroll
  for (int nf = 0; nf < 4; ++nf) {
    const int col = n0 + wn * 64 + nf * 16 + cc;
    const float bv = bias[col];
#pragma unroll
    for (int mf = 0; mf < 8; ++mf) {
      const int row0 = m0 + wm * 128 + mf * 16 + kg * 4;
      float* op = Out + (size_t)row0 * N_DIM + col;
#pragma unroll
      for (int j = 0; j < 4; ++j)
        op[(size_t)j * N_DIM] = acc[mf][nf][j] + bv;
    }
  }
#undef GROUP
#undef MFMA8
#undef STAGE_B
#undef AWRITE
#undef ALOAD
#undef READ_A
#undef READ_B
#undef RD
#undef SB0
#undef BAR
#undef LGKM0
#undef GATE6
#undef GATE0
#undef NOGATE
}

// ---------------- fallback (ws too small): naive fp32 ----------------------
__global__ __launch_bounds__(256) void toeplitz_naive(
    const float* __restrict__ x, const float* __restrict__ fr,
    const float* __restrict__ fc, const float* __restrict__ bias,
    float* __restrict__ out) {
  __shared__ float sx[1024], sfr[1024], sfc[1024];
  const int m = blockIdx.x;
  for (int i = threadIdx.x; i < 1024; i += 256) {
    sx[i]  = x[(size_t)m * 1024 + i];
    sfr[i] = fr[i];
    sfc[i] = fc[i];
  }
  __syncthreads();
  for (int q = 0; q < 4; ++q) {
    const int o = threadIdx.x + q * 256;
    float acc = bias[o];
    for (int i = 0; i <= o; ++i)       acc += sx[i] * sfc[o - i];
    for (int i = o + 1; i < 1024; ++i) acc += sx[i] * sfr[i - o];
    out[(size_t)m * 1024 + o] = acc;
  }
}

extern "C" void kernel_launch(void* const* d_in, const int* in_sizes, int n_in,
                              void* d_out, int out_size, void* d_ws, size_t ws_size,
                              hipStream_t stream) {
  const float* x    = (const float*)d_in[0];
  const float* fr   = (const float*)d_in[1];
  const float* fc   = (const float*)d_in[2];
  const float* bias = (const float*)d_in[3];
  float* out = (float*)d_out;

  if (ws_size >= (size_t)2 * 1024 * 1024) {
    ushort* T = (ushort*)d_ws;
    build_T_kernel<<<dim3(512), dim3(256), 0, stream>>>(fr, fc, T);
    gemm_fused_8p<<<dim3(512), dim3(512), 0, stream>>>(x, T, bias, out);
  } else {
    toeplitz_naive<<<dim3(32768), dim3(256), 0, stream>>>(x, fr, fc, bias, out);
  }
}